// Round 1
// baseline (155.320 us; speedup 1.0000x reference)
//
#include <hip/hip_runtime.h>
#include <hip/hip_bf16.h>

#define B_DIM  8192
#define IN_DIM 1024
#define H_DIM  1024
#define K_DIM  2048   // IN + H

typedef __attribute__((ext_vector_type(8))) short bf16x8;
typedef __attribute__((ext_vector_type(4))) float f32x4;

// Inline-asm MFMA: avoids builtin operand-type roulette (short8 vs v8bf16).
// D=%0 (f32x4), A=%1, B=%2 (4 VGPRs each), C=%0.
__device__ __forceinline__ void mfma_16x16x32_bf16(f32x4& d, const bf16x8& a, const bf16x8& b) {
  asm("v_mfma_f32_16x16x32_bf16 %0, %1, %2, %0" : "+v"(d) : "v"(a), "v"(b));
}

// async global->LDS, 16B per lane; LDS dest = wave-uniform base + lane*16.
__device__ __forceinline__ void gload16(const void* g, void* l) {
  __builtin_amdgcn_global_load_lds(
      (const __attribute__((address_space(1))) void*)g,
      (__attribute__((address_space(3))) void*)l,
      16, 0, 0);
}

__device__ __forceinline__ float fast_sigmoid(float x) {
  return 1.0f / (1.0f + __expf(-x));
}
// overflow-safe tanh: x->+inf => 1, x->-inf => -1 (no inf/inf NaN)
__device__ __forceinline__ float fast_tanh(float x) {
  float e = __expf(2.0f * x);
  return 1.0f - 2.0f / (e + 1.0f);
}

// ---------------- pack kernels: fp32 -> bf16, concatenated layouts ----------
// A[r][k]: k<1024 -> x[r][k], else hx[r][k-1024].  8 elems/thread.
__global__ __launch_bounds__(256) void pack_a_kernel(
    const float* __restrict__ x, const float* __restrict__ hx,
    __hip_bfloat16* __restrict__ A) {
  const int idx = blockIdx.x * 256 + threadIdx.x;
  const int r  = idx >> 8;           // 256 groups of 8 per 2048-col row
  const int kk = (idx & 255) << 3;
  const float* src = (kk < IN_DIM) ? (x + (size_t)r * IN_DIM + kk)
                                   : (hx + (size_t)r * H_DIM + (kk - IN_DIM));
  const float4 v0 = ((const float4*)src)[0];
  const float4 v1 = ((const float4*)src)[1];
  __hip_bfloat16 t[8];
  t[0] = __float2bfloat16(v0.x); t[1] = __float2bfloat16(v0.y);
  t[2] = __float2bfloat16(v0.z); t[3] = __float2bfloat16(v0.w);
  t[4] = __float2bfloat16(v1.x); t[5] = __float2bfloat16(v1.y);
  t[6] = __float2bfloat16(v1.z); t[7] = __float2bfloat16(v1.w);
  *(uint4*)(A + ((size_t)idx << 3)) = *(const uint4*)t;
}

// W[g*1024+n][k]: k<1024 -> wx_g[n][k], else wh_g[n][k-1024]. gate order i,f,c,o
__global__ __launch_bounds__(256) void pack_w_kernel(
    const float* __restrict__ wxi, const float* __restrict__ wxf,
    const float* __restrict__ wxc, const float* __restrict__ wxo,
    const float* __restrict__ whi, const float* __restrict__ whf,
    const float* __restrict__ whc, const float* __restrict__ who,
    __hip_bfloat16* __restrict__ W) {
  const int idx = blockIdx.x * 256 + threadIdx.x;
  const int row = idx >> 8;          // 0..4095 = g*1024 + n
  const int kk  = (idx & 255) << 3;
  const int g = row >> 10, n = row & 1023;
  const float* src;
  if (kk < IN_DIM) {
    const float* p = (g == 0) ? wxi : (g == 1) ? wxf : (g == 2) ? wxc : wxo;
    src = p + (size_t)n * IN_DIM + kk;
  } else {
    const float* p = (g == 0) ? whi : (g == 1) ? whf : (g == 2) ? whc : who;
    src = p + (size_t)n * H_DIM + (kk - IN_DIM);
  }
  const float4 v0 = ((const float4*)src)[0];
  const float4 v1 = ((const float4*)src)[1];
  __hip_bfloat16 t[8];
  t[0] = __float2bfloat16(v0.x); t[1] = __float2bfloat16(v0.y);
  t[2] = __float2bfloat16(v0.z); t[3] = __float2bfloat16(v0.w);
  t[4] = __float2bfloat16(v1.x); t[5] = __float2bfloat16(v1.y);
  t[6] = __float2bfloat16(v1.z); t[7] = __float2bfloat16(v1.w);
  *(uint4*)(W + ((size_t)idx << 3)) = *(const uint4*)t;
}

// ---------------- fused GEMM + LSTM gate epilogue ---------------------------
// Block: BM=128 batch rows x BN=64 h-cols, all 4 gates accumulated.
// 4 waves in 2x2; each wave 64x32; frags: 4(m) x 2(n) x 4(gate) f32x4 accs.
// LDS: sA[128][64] (16KB) + sW[4][64][64] (32KB) single-buffered.
// XOR swizzle: LDS content [row][c] = G[row][c ^ (row&7)] (16B chunks), done by
// pre-swizzling the per-lane GLOBAL source column (global_load_lds dest must be
// linear); ds_read side applies the same XOR.
__global__ __launch_bounds__(256, 2) void lstm_gemm_kernel(
    const __hip_bfloat16* __restrict__ A,   // [8192][2048]
    const __hip_bfloat16* __restrict__ W,   // [4096][2048] gate-major
    const float* __restrict__ cx,
    const float* __restrict__ bxi, const float* __restrict__ bhi,
    const float* __restrict__ bxf, const float* __restrict__ bhf,
    const float* __restrict__ bxc, const float* __restrict__ bhc,
    const float* __restrict__ bxo, const float* __restrict__ bho,
    float* __restrict__ hy, float* __restrict__ cy) {

  __shared__ __align__(16) __hip_bfloat16 sA[128][64];
  __shared__ __align__(16) __hip_bfloat16 sW[4][64][64];

  const int tid  = threadIdx.x;
  const int w    = tid >> 6;        // wave 0..3
  const int lane = tid & 63;
  const int wm = w >> 1, wn = w & 1;          // 2x2 wave grid
  const int lq = lane >> 4, lr16 = lane & 15; // mfma lane decomposition

  const int row0 = blockIdx.x * 128;  // batch tile
  const int col0 = blockIdx.y * 64;   // h tile

  // staging geometry: 64 lanes cover 8 rows x 8 chunks(16B) = 1KB per pass
  const int sr  = lane >> 3;       // row within 8-row stripe (== fr&7)
  const int sc  = lane & 7;        // linear dest chunk
  const int scs = sc ^ sr;         // pre-swizzled source chunk

  f32x4 acc[4][4][2];
#pragma unroll
  for (int g = 0; g < 4; ++g)
#pragma unroll
    for (int m = 0; m < 4; ++m)
#pragma unroll
      for (int nf = 0; nf < 2; ++nf)
        acc[g][m][nf] = (f32x4){0.f, 0.f, 0.f, 0.f};

  for (int kt = 0; kt < K_DIM / 64; ++kt) {
    const int k0 = kt * 64;
    // stage A: 16 stripes of 1KB, 4 per wave
#pragma unroll
    for (int it = 0; it < 4; ++it) {
      const int stripe = it * 4 + w;              // 0..15
      const int fr = stripe * 8 + sr;             // 0..127
      const __hip_bfloat16* src = A + (size_t)(row0 + fr) * K_DIM + k0 + scs * 8;
      gload16(src, (char*)(&sA[0][0]) + stripe * 1024);
    }
    // stage W: 32 stripes, 8 per wave  (flat row fr = g*64 + n)
#pragma unroll
    for (int it = 0; it < 8; ++it) {
      const int stripe = it * 4 + w;              // 0..31
      const int fr = stripe * 8 + sr;             // 0..255
      const int g = fr >> 6, n = fr & 63;
      const __hip_bfloat16* src =
          W + ((size_t)(g << 10) + col0 + n) * K_DIM + k0 + scs * 8;
      gload16(src, (char*)(&sW[0][0][0]) + stripe * 1024);
    }
    __syncthreads();   // compiler drains vmcnt before s_barrier

#pragma unroll
    for (int ks = 0; ks < 2; ++ks) {
      bf16x8 af[4];
#pragma unroll
      for (int m = 0; m < 4; ++m) {
        const int row = wm * 64 + m * 16 + lr16;
        const int ch  = (ks * 4 + lq) ^ (row & 7);
        af[m] = *(const bf16x8*)&sA[row][ch * 8];
      }
#pragma unroll
      for (int g = 0; g < 4; ++g) {
        bf16x8 bfv[2];
#pragma unroll
        for (int nf = 0; nf < 2; ++nf) {
          const int n  = wn * 32 + nf * 16 + lr16;
          const int ch = (ks * 4 + lq) ^ (n & 7);
          bfv[nf] = *(const bf16x8*)&sW[g][n][ch * 8];
        }
#pragma unroll
        for (int m = 0; m < 4; ++m)
#pragma unroll
          for (int nf = 0; nf < 2; ++nf)
            mfma_16x16x32_bf16(acc[g][m][nf], af[m], bfv[nf]);
      }
    }
    __syncthreads();
  }

  // epilogue: gates + cell update, fp32 out
#pragma unroll
  for (int nf = 0; nf < 2; ++nf) {
    const int h = col0 + wn * 32 + nf * 16 + lr16;
    const float bi = bxi[h] + bhi[h];
    const float bf = bxf[h] + bhf[h];
    const float bc = bxc[h] + bhc[h];
    const float bo = bxo[h] + bho[h];
#pragma unroll
    for (int m = 0; m < 4; ++m) {
#pragma unroll
      for (int j = 0; j < 4; ++j) {
        const int r = row0 + wm * 64 + m * 16 + lq * 4 + j;  // D row mapping
        const size_t o = (size_t)r * H_DIM + h;
        const float ig = fast_sigmoid(acc[0][m][nf][j] + bi);
        const float fg = fast_sigmoid(acc[1][m][nf][j] + bf);
        const float gg = fast_tanh   (acc[2][m][nf][j] + bc);
        const float og = fast_sigmoid(acc[3][m][nf][j] + bo);
        const float c  = cx[o] * fg + ig * gg;
        cy[o] = c;
        hy[o] = og * fast_tanh(c);
      }
    }
  }
}

extern "C" void kernel_launch(void* const* d_in, const int* in_sizes, int n_in,
                              void* d_out, int out_size, void* d_ws, size_t ws_size,
                              hipStream_t stream) {
  const float* x   = (const float*)d_in[0];
  const float* hx  = (const float*)d_in[1];
  const float* cx  = (const float*)d_in[2];
  // d_in[3] = task_id (unused)
  const float* wxi = (const float*)d_in[4];  const float* bxi = (const float*)d_in[5];
  const float* wxf = (const float*)d_in[6];  const float* bxf = (const float*)d_in[7];
  const float* wxc = (const float*)d_in[8];  const float* bxc = (const float*)d_in[9];
  const float* wxo = (const float*)d_in[10]; const float* bxo = (const float*)d_in[11];
  const float* whi = (const float*)d_in[12]; const float* bhi = (const float*)d_in[13];
  const float* whf = (const float*)d_in[14]; const float* bhf = (const float*)d_in[15];
  const float* whc = (const float*)d_in[16]; const float* bhc = (const float*)d_in[17];
  const float* who = (const float*)d_in[18]; const float* bho = (const float*)d_in[19];

  __hip_bfloat16* Abf = (__hip_bfloat16*)d_ws;                       // 32 MB
  __hip_bfloat16* Wbf = (__hip_bfloat16*)((char*)d_ws + (size_t)B_DIM * K_DIM * 2); // 16 MB

  float* hy  = (float*)d_out;
  float* cyo = (float*)d_out + (size_t)B_DIM * H_DIM;

  pack_a_kernel<<<(B_DIM * K_DIM / 8) / 256, 256, 0, stream>>>(x, hx, Abf);
  pack_w_kernel<<<(4 * H_DIM * K_DIM / 8) / 256, 256, 0, stream>>>(
      wxi, wxf, wxc, wxo, whi, whf, whc, who, Wbf);

  dim3 grid(B_DIM / 128, H_DIM / 64);
  lstm_gemm_kernel<<<grid, 256, 0, stream>>>(
      Abf, Wbf, cx, bxi, bhi, bxf, bhf, bxc, bhc, bxo, bho, hy, cyo);
}